// Round 1
// baseline (1768.977 us; speedup 1.0000x reference)
//
#include <hip/hip_runtime.h>

#define N_NODES 50000
#define N_EDGES 800000
#define IN_CH   128
#define OUT_CH  32
#define HEADS   10
#define HC      320           // HEADS*OUT_CH
#define N_GRAPHS 512
#define NEG_SLOPE 0.2f

// ---- order-preserving float<->uint map for atomicMax-based segment_max ----
__device__ __forceinline__ unsigned fmap(float f) {
  unsigned u = __float_as_uint(f);
  return (u & 0x80000000u) ? ~u : (u | 0x80000000u);
}
__device__ __forceinline__ float funmap(unsigned u) {
  u = (u & 0x80000000u) ? (u ^ 0x80000000u) : ~u;
  return __uint_as_float(u);
}

// ---------------- GEMM1: h1[N,320] = x[N,128] @ W1[128,320] ----------------
// 64x64 tile, BK=32, 256 threads, 4x4 per thread. f32 vector ALU.
__global__ __launch_bounds__(256) void gemm1(const float* __restrict__ X,
                                             const float* __restrict__ W,
                                             float* __restrict__ Hout) {
  __shared__ float As[32][65];   // [k][n]
  __shared__ float Bs[32][64];   // [k][j]
  const int n0 = blockIdx.y * 64;
  const int j0 = blockIdx.x * 64;
  const int tid = threadIdx.y * 16 + threadIdx.x;
  float acc[4][4] = {};
  for (int k0 = 0; k0 < IN_CH; k0 += 32) {
    #pragma unroll
    for (int i = 0; i < 8; i++) {
      int idx = tid + 256 * i;
      int n = idx >> 5, k = idx & 31;
      int nn = n0 + n;
      As[k][n] = (nn < N_NODES) ? X[(size_t)nn * IN_CH + k0 + k] : 0.f;
    }
    #pragma unroll
    for (int i = 0; i < 8; i++) {
      int idx = tid + 256 * i;
      int k = idx >> 6, j = idx & 63;
      Bs[k][j] = W[(size_t)(k0 + k) * HC + j0 + j];
    }
    __syncthreads();
    #pragma unroll
    for (int k = 0; k < 32; k++) {
      float a[4], b[4];
      #pragma unroll
      for (int i = 0; i < 4; i++) a[i] = As[k][threadIdx.y + 16 * i];
      #pragma unroll
      for (int j = 0; j < 4; j++) b[j] = Bs[k][threadIdx.x + 16 * j];
      #pragma unroll
      for (int i = 0; i < 4; i++)
        #pragma unroll
        for (int j = 0; j < 4; j++) acc[i][j] += a[i] * b[j];
    }
    __syncthreads();
  }
  #pragma unroll
  for (int i = 0; i < 4; i++) {
    int n = n0 + threadIdx.y + 16 * i;
    if (n >= N_NODES) continue;
    #pragma unroll
    for (int j = 0; j < 4; j++)
      Hout[(size_t)n * HC + j0 + threadIdx.x + 16 * j] = acc[i][j];
  }
}

// -------- e_src/e_dst per (node, head): dot(h1[n,h,:], a_src[h,:]) ---------
__global__ __launch_bounds__(256) void edot1(const float* __restrict__ h1,
                                             const float* __restrict__ a_src,
                                             const float* __restrict__ a_dst,
                                             float* __restrict__ es,
                                             float* __restrict__ ed) {
  int idx = blockIdx.x * 256 + threadIdx.x;
  if (idx >= N_NODES * HEADS) return;
  int n = idx / HEADS, h = idx - n * HEADS;
  const float4* hp = reinterpret_cast<const float4*>(h1 + (size_t)n * HC + h * OUT_CH);
  const float4* ap = reinterpret_cast<const float4*>(a_src + h * OUT_CH);
  const float4* bp = reinterpret_cast<const float4*>(a_dst + h * OUT_CH);
  float s = 0.f, d = 0.f;
  #pragma unroll
  for (int q = 0; q < 8; q++) {
    float4 hv = hp[q], av = ap[q], dv = bp[q];
    s += hv.x * av.x + hv.y * av.y + hv.z * av.z + hv.w * av.w;
    d += hv.x * dv.x + hv.y * dv.y + hv.z * dv.z + hv.w * dv.w;
  }
  es[idx] = s; ed[idx] = d;
}

// ---------------- edge pass 1 (layer1): segment max of alpha ---------------
__global__ __launch_bounds__(256) void edge_max1(const int* __restrict__ ei,
                                                 const float* __restrict__ es,
                                                 const float* __restrict__ ed,
                                                 unsigned* __restrict__ amax) {
  int stride = gridDim.x * blockDim.x;
  for (int e = blockIdx.x * blockDim.x + threadIdx.x; e < N_EDGES; e += stride) {
    int src = ei[e], dst = ei[N_EDGES + e];
    #pragma unroll
    for (int h = 0; h < HEADS; h++) {
      float a = es[src * HEADS + h] + ed[dst * HEADS + h];
      a = a > 0.f ? a : NEG_SLOPE * a;
      atomicMax(&amax[dst * HEADS + h], fmap(a));
    }
  }
}

// ------- edge pass 2 (layer1): accum[dst,h,c] += h1[src,h,c]*ex ; denom ----
__global__ __launch_bounds__(320) void edge_acc1(const int* __restrict__ ei,
                                                 const float* __restrict__ es,
                                                 const float* __restrict__ ed,
                                                 const unsigned* __restrict__ amax,
                                                 const float* __restrict__ h1,
                                                 float* __restrict__ accum,
                                                 float* __restrict__ denom) {
  const int t = threadIdx.x;        // 0..319 = h*32+c
  const int h = t >> 5;
  for (int e = blockIdx.x; e < N_EDGES; e += gridDim.x) {
    int src = ei[e], dst = ei[N_EDGES + e];
    float a = es[src * HEADS + h] + ed[dst * HEADS + h];
    a = a > 0.f ? a : NEG_SLOPE * a;
    unsigned mu = amax[dst * HEADS + h];
    float m = (mu == 0u) ? 0.f : funmap(mu);
    float ex = expf(a - m);
    float v = h1[(size_t)src * HC + t] * ex;
    atomicAdd(&accum[(size_t)dst * HC + t], v);
    if ((t & 31) == 0) atomicAdd(&denom[dst * HEADS + h], ex);
  }
}

// --------- act1[n,i] = elu(accum/(denom+eps) + b1)  (float4 over N*320) ----
__global__ __launch_bounds__(256) void act1_k(const float* __restrict__ accum,
                                              const float* __restrict__ denom,
                                              const float* __restrict__ b1,
                                              float* __restrict__ act) {
  int i4 = blockIdx.x * 256 + threadIdx.x;       // float4 index over N*80
  if (i4 >= N_NODES * 80) return;
  int n = i4 / 80;
  int r = i4 - n * 80;                            // float4 within row
  int h = r >> 3;
  float dn = denom[n * HEADS + h] + 1e-16f;
  float inv = 1.f / dn;
  float4 ac = reinterpret_cast<const float4*>(accum)[i4];
  float4 bb = reinterpret_cast<const float4*>(b1)[r];
  float4 o;
  float v;
  v = ac.x * inv + bb.x; o.x = v > 0.f ? v : expm1f(v);
  v = ac.y * inv + bb.y; o.y = v > 0.f ? v : expm1f(v);
  v = ac.z * inv + bb.z; o.z = v > 0.f ? v : expm1f(v);
  v = ac.w * inv + bb.w; o.w = v > 0.f ? v : expm1f(v);
  reinterpret_cast<float4*>(act)[i4] = o;
}

// ---------------- GEMM2: h2[N,32] = act[N,320] @ W2[320,32] ----------------
__global__ __launch_bounds__(256) void gemm2(const float* __restrict__ A,
                                             const float* __restrict__ W,
                                             float* __restrict__ Hout) {
  __shared__ float As[32][65];   // [k][n]
  __shared__ float Bs[32][32];   // [k][j]
  const int n0 = blockIdx.x * 64;
  const int tx = threadIdx.x;    // 0..31 -> j
  const int ty = threadIdx.y;    // 0..7
  const int tid = ty * 32 + tx;
  float acc[8] = {};
  for (int k0 = 0; k0 < HC; k0 += 32) {
    #pragma unroll
    for (int i = 0; i < 8; i++) {
      int idx = tid + 256 * i;
      int n = idx >> 5, k = idx & 31;
      int nn = n0 + n;
      As[k][n] = (nn < N_NODES) ? A[(size_t)nn * HC + k0 + k] : 0.f;
    }
    #pragma unroll
    for (int i = 0; i < 4; i++) {
      int idx = tid + 256 * i;
      int k = idx >> 5, j = idx & 31;
      Bs[k][j] = W[(size_t)(k0 + k) * OUT_CH + j];
    }
    __syncthreads();
    #pragma unroll
    for (int k = 0; k < 32; k++) {
      float b = Bs[k][tx];
      #pragma unroll
      for (int i = 0; i < 8; i++) acc[i] += As[k][ty + 8 * i] * b;
    }
    __syncthreads();
  }
  #pragma unroll
  for (int i = 0; i < 8; i++) {
    int n = n0 + ty + 8 * i;
    if (n < N_NODES) Hout[(size_t)n * OUT_CH + tx] = acc[i];
  }
}

// ---------------- e_src2/e_dst2 per node (H=1) -----------------------------
__global__ __launch_bounds__(256) void edot2(const float* __restrict__ h2,
                                             const float* __restrict__ a_src,
                                             const float* __restrict__ a_dst,
                                             float* __restrict__ es,
                                             float* __restrict__ ed) {
  int n = blockIdx.x * 256 + threadIdx.x;
  if (n >= N_NODES) return;
  const float4* hp = reinterpret_cast<const float4*>(h2 + (size_t)n * OUT_CH);
  const float4* ap = reinterpret_cast<const float4*>(a_src);
  const float4* bp = reinterpret_cast<const float4*>(a_dst);
  float s = 0.f, d = 0.f;
  #pragma unroll
  for (int q = 0; q < 8; q++) {
    float4 hv = hp[q], av = ap[q], dv = bp[q];
    s += hv.x * av.x + hv.y * av.y + hv.z * av.z + hv.w * av.w;
    d += hv.x * dv.x + hv.y * dv.y + hv.z * dv.z + hv.w * dv.w;
  }
  es[n] = s; ed[n] = d;
}

__global__ __launch_bounds__(256) void edge_max2(const int* __restrict__ ei,
                                                 const float* __restrict__ es,
                                                 const float* __restrict__ ed,
                                                 unsigned* __restrict__ amax) {
  int stride = gridDim.x * blockDim.x;
  for (int e = blockIdx.x * blockDim.x + threadIdx.x; e < N_EDGES; e += stride) {
    int src = ei[e], dst = ei[N_EDGES + e];
    float a = es[src] + ed[dst];
    a = a > 0.f ? a : NEG_SLOPE * a;
    atomicMax(&amax[dst], fmap(a));
  }
}

__global__ __launch_bounds__(256) void edge_acc2(const int* __restrict__ ei,
                                                 const float* __restrict__ es,
                                                 const float* __restrict__ ed,
                                                 const unsigned* __restrict__ amax,
                                                 const float* __restrict__ h2,
                                                 float* __restrict__ accum,
                                                 float* __restrict__ denom) {
  const int c = threadIdx.x & 31;
  const int sub = threadIdx.x >> 5;   // 0..7
  const int estep = gridDim.x * 8;
  for (int e = blockIdx.x * 8 + sub; e < N_EDGES; e += estep) {
    int src = ei[e], dst = ei[N_EDGES + e];
    float a = es[src] + ed[dst];
    a = a > 0.f ? a : NEG_SLOPE * a;
    unsigned mu = amax[dst];
    float m = (mu == 0u) ? 0.f : funmap(mu);
    float ex = expf(a - m);
    atomicAdd(&accum[(size_t)dst * OUT_CH + c], h2[(size_t)src * OUT_CH + c] * ex);
    if (c == 0) atomicAdd(&denom[dst], ex);
  }
}

// -------- act2 + global max pool:  pooled[g,c] = max over nodes ------------
__global__ __launch_bounds__(256) void pool_k(const float* __restrict__ accum,
                                              const float* __restrict__ denom,
                                              const float* __restrict__ b2,
                                              const int* __restrict__ batch,
                                              unsigned* __restrict__ pooled) {
  int idx = blockIdx.x * 256 + threadIdx.x;
  if (idx >= N_NODES * OUT_CH) return;
  int n = idx >> 5, c = idx & 31;
  float v = accum[idx] / (denom[n] + 1e-16f) + b2[c];
  v = v > 0.f ? v : expm1f(v);
  int g = batch[n];
  atomicMax(&pooled[g * OUT_CH + c], fmap(v));
}

// -------- final: out[g,c] = relu(pooled[g,:] @ fc_w[:,c] + fc_b[c]) --------
__global__ __launch_bounds__(256) void final_k(const unsigned* __restrict__ pooled,
                                               const float* __restrict__ fc_w,
                                               const float* __restrict__ fc_b,
                                               float* __restrict__ out) {
  int idx = blockIdx.x * 256 + threadIdx.x;
  if (idx >= N_GRAPHS * OUT_CH) return;
  int g = idx >> 5, c = idx & 31;
  float s = fc_b[c];
  #pragma unroll
  for (int k = 0; k < OUT_CH; k++) {
    unsigned u = pooled[g * OUT_CH + k];
    float p = (u == 0u) ? 0.f : funmap(u);
    s += p * fc_w[k * OUT_CH + c];
  }
  out[idx] = s > 0.f ? s : 0.f;
}

extern "C" void kernel_launch(void* const* d_in, const int* in_sizes, int n_in,
                              void* d_out, int out_size, void* d_ws, size_t ws_size,
                              hipStream_t stream) {
  const float* x      = (const float*)d_in[0];
  const int*   ei     = (const int*)d_in[1];
  const int*   batch  = (const int*)d_in[2];
  const float* W1     = (const float*)d_in[4];
  const float* a_src1 = (const float*)d_in[5];
  const float* a_dst1 = (const float*)d_in[6];
  const float* b1     = (const float*)d_in[7];
  const float* W2     = (const float*)d_in[8];
  const float* a_src2 = (const float*)d_in[9];
  const float* a_dst2 = (const float*)d_in[10];
  const float* b2     = (const float*)d_in[11];
  const float* fc_w   = (const float*)d_in[12];
  const float* fc_b   = (const float*)d_in[13];
  float* out = (float*)d_out;

  // ---- workspace layout (136 MB total) ----
  char* ws = (char*)d_ws;
  float*    h1     = (float*)(ws);                         // 64 MB (A) — h1, later dead
  float*    accum1 = (float*)(ws + 64000000);              // 64 MB (B) — accum1 -> act1 in place
  char*     C      = ws + 128000000;                       //  8 MB small buffers
  float*    e_src1 = (float*)(C);                          // 2 MB (later e_src2)
  float*    e_dst1 = (float*)(C + 2000000);                // 2 MB (later e_dst2)
  unsigned* amax1  = (unsigned*)(C + 4000000);             // 2 MB (later amax2)
  float*    denom1 = (float*)(C + 6000000);                // 2 MB (later denom2)
  unsigned* pooled = (unsigned*)(C + 7000000);             // 64 KB (denom1 dead by then)
  // layer-2 aliases
  float*    h2     = (float*)(ws);                         // into A (h1 dead after act1? h1 read in edge_acc1; act written to B; A dead after edge_acc1)
  float*    accum2 = (float*)(ws + 8000000);               // into A, disjoint from h2 (6.4MB < 8MB)
  float*    act1   = accum1;                               // act1 written in place over accum1 region? NO — see below
  // NOTE: act1 must be a separate buffer from accum1 input? act1_k reads accum1
  // and writes elementwise to the SAME index — safe in place. Use accum1 region.

  float*    es2 = e_src1;  float* ed2 = e_dst1;
  unsigned* amax2 = amax1; float* denom2 = denom1;

  // ---- layer 1 ----
  hipMemsetAsync(amax1,  0, (size_t)N_NODES * HEADS * 4, stream);
  hipMemsetAsync(denom1, 0, (size_t)N_NODES * HEADS * 4, stream);
  hipMemsetAsync(accum1, 0, (size_t)N_NODES * HC * 4, stream);

  gemm1<<<dim3(HC / 64, (N_NODES + 63) / 64), dim3(16, 16), 0, stream>>>(x, W1, h1);
  edot1<<<(N_NODES * HEADS + 255) / 256, 256, 0, stream>>>(h1, a_src1, a_dst1, e_src1, e_dst1);
  edge_max1<<<2048, 256, 0, stream>>>(ei, e_src1, e_dst1, amax1);
  edge_acc1<<<8192, 320, 0, stream>>>(ei, e_src1, e_dst1, amax1, h1, accum1, denom1);
  // act1 in place over accum1 (elementwise, same index)
  act1_k<<<(N_NODES * 80 + 255) / 256, 256, 0, stream>>>(accum1, denom1, b1, act1);

  // ---- layer 2 (h1/A region dead; small buffers reused) ----
  hipMemsetAsync(amax2,  0, (size_t)N_NODES * 4, stream);
  hipMemsetAsync(denom2, 0, (size_t)N_NODES * 4, stream);
  hipMemsetAsync(accum2, 0, (size_t)N_NODES * OUT_CH * 4, stream);
  hipMemsetAsync(pooled, 0, (size_t)N_GRAPHS * OUT_CH * 4, stream);

  gemm2<<<dim3((N_NODES + 63) / 64), dim3(32, 8), 0, stream>>>(act1, W2, h2);
  edot2<<<(N_NODES + 255) / 256, 256, 0, stream>>>(h2, a_src2, a_dst2, es2, ed2);
  edge_max2<<<2048, 256, 0, stream>>>(ei, es2, ed2, amax2);
  edge_acc2<<<8192, 256, 0, stream>>>(ei, es2, ed2, amax2, h2, accum2, denom2);
  pool_k<<<(N_NODES * OUT_CH + 255) / 256, 256, 0, stream>>>(accum2, denom2, b2, batch, pooled);
  final_k<<<(N_GRAPHS * OUT_CH + 255) / 256, 256, 0, stream>>>(pooled, fc_w, fc_b, out);
}

// Round 2
// 585.495 us; speedup vs baseline: 3.0213x; 3.0213x over previous
//
#include <hip/hip_runtime.h>

#define N_NODES 50000
#define N_EDGES 800000
#define IN_CH   128
#define OUT_CH  32
#define HEADS   10
#define HC      320           // HEADS*OUT_CH
#define N_GRAPHS 512
#define NEG_SLOPE 0.2f
#define NBLK_SCAN 196         // ceil(50000/256)

// ---- order-preserving float<->uint map for atomicMax-based segment_max ----
__device__ __forceinline__ unsigned fmap(float f) {
  unsigned u = __float_as_uint(f);
  return (u & 0x80000000u) ? ~u : (u | 0x80000000u);
}
__device__ __forceinline__ float funmap(unsigned u) {
  u = (u & 0x80000000u) ? (u ^ 0x80000000u) : ~u;
  return __uint_as_float(u);
}

// ============================ CSR construction =============================
__global__ __launch_bounds__(256) void hist_k(const int* __restrict__ ei,
                                              int* __restrict__ deg) {
  int e = blockIdx.x * 256 + threadIdx.x;
  if (e < N_EDGES) atomicAdd(&deg[ei[N_EDGES + e]], 1);
}

// per-block exclusive scan of deg -> roff; block totals -> bsum
__global__ __launch_bounds__(256) void scan_blk(const int* __restrict__ deg,
                                                int* __restrict__ roff,
                                                int* __restrict__ bsum) {
  __shared__ int s[256];
  int i = blockIdx.x * 256 + threadIdx.x;
  int v = (i < N_NODES) ? deg[i] : 0;
  s[threadIdx.x] = v;
  __syncthreads();
  #pragma unroll
  for (int o = 1; o < 256; o <<= 1) {
    int t = (threadIdx.x >= o) ? s[threadIdx.x - o] : 0;
    __syncthreads();
    s[threadIdx.x] += t;
    __syncthreads();
  }
  if (i < N_NODES) roff[i] = s[threadIdx.x] - v;   // exclusive
  if (threadIdx.x == 255) bsum[blockIdx.x] = s[255];
}

__global__ __launch_bounds__(256) void scan_top(int* __restrict__ bsum) {
  __shared__ int s[256];
  int i = threadIdx.x;
  int v = (i < NBLK_SCAN) ? bsum[i] : 0;
  s[i] = v;
  __syncthreads();
  #pragma unroll
  for (int o = 1; o < 256; o <<= 1) {
    int t = (i >= o) ? s[i - o] : 0;
    __syncthreads();
    s[i] += t;
    __syncthreads();
  }
  if (i < NBLK_SCAN) bsum[i] = s[i] - v;           // exclusive
}

__global__ __launch_bounds__(256) void scan_add(int* __restrict__ roff,
                                                const int* __restrict__ bsum) {
  int i = blockIdx.x * 256 + threadIdx.x;
  if (i < N_NODES) roff[i] += bsum[blockIdx.x];
  if (i == 0) roff[N_NODES] = N_EDGES;
}

__global__ __launch_bounds__(256) void scatter_k(const int* __restrict__ ei,
                                                 const int* __restrict__ roff,
                                                 int* __restrict__ cursor,
                                                 int* __restrict__ ssrc) {
  int e = blockIdx.x * 256 + threadIdx.x;
  if (e >= N_EDGES) return;
  int dst = ei[N_EDGES + e];
  int pos = roff[dst] + atomicAdd(&cursor[dst], 1);
  ssrc[pos] = ei[e];
}

// ---------------- GEMM1: h1[N,320] = x[N,128] @ W1[128,320] ----------------
__global__ __launch_bounds__(256) void gemm1(const float* __restrict__ X,
                                             const float* __restrict__ W,
                                             float* __restrict__ Hout) {
  __shared__ float As[32][65];
  __shared__ float Bs[32][64];
  const int n0 = blockIdx.y * 64;
  const int j0 = blockIdx.x * 64;
  const int tid = threadIdx.y * 16 + threadIdx.x;
  float acc[4][4] = {};
  for (int k0 = 0; k0 < IN_CH; k0 += 32) {
    #pragma unroll
    for (int i = 0; i < 8; i++) {
      int idx = tid + 256 * i;
      int n = idx >> 5, k = idx & 31;
      int nn = n0 + n;
      As[k][n] = (nn < N_NODES) ? X[(size_t)nn * IN_CH + k0 + k] : 0.f;
    }
    #pragma unroll
    for (int i = 0; i < 8; i++) {
      int idx = tid + 256 * i;
      int k = idx >> 6, j = idx & 63;
      Bs[k][j] = W[(size_t)(k0 + k) * HC + j0 + j];
    }
    __syncthreads();
    #pragma unroll
    for (int k = 0; k < 32; k++) {
      float a[4], b[4];
      #pragma unroll
      for (int i = 0; i < 4; i++) a[i] = As[k][threadIdx.y + 16 * i];
      #pragma unroll
      for (int j = 0; j < 4; j++) b[j] = Bs[k][threadIdx.x + 16 * j];
      #pragma unroll
      for (int i = 0; i < 4; i++)
        #pragma unroll
        for (int j = 0; j < 4; j++) acc[i][j] += a[i] * b[j];
    }
    __syncthreads();
  }
  #pragma unroll
  for (int i = 0; i < 4; i++) {
    int n = n0 + threadIdx.y + 16 * i;
    if (n >= N_NODES) continue;
    #pragma unroll
    for (int j = 0; j < 4; j++)
      Hout[(size_t)n * HC + j0 + threadIdx.x + 16 * j] = acc[i][j];
  }
}

// -------- e_src/e_dst per (node, head): dot(h1[n,h,:], a_src[h,:]) ---------
__global__ __launch_bounds__(256) void edot1(const float* __restrict__ h1,
                                             const float* __restrict__ a_src,
                                             const float* __restrict__ a_dst,
                                             float* __restrict__ es,
                                             float* __restrict__ ed) {
  int idx = blockIdx.x * 256 + threadIdx.x;
  if (idx >= N_NODES * HEADS) return;
  int n = idx / HEADS, h = idx - n * HEADS;
  const float4* hp = reinterpret_cast<const float4*>(h1 + (size_t)n * HC + h * OUT_CH);
  const float4* ap = reinterpret_cast<const float4*>(a_src + h * OUT_CH);
  const float4* bp = reinterpret_cast<const float4*>(a_dst + h * OUT_CH);
  float s = 0.f, d = 0.f;
  #pragma unroll
  for (int q = 0; q < 8; q++) {
    float4 hv = hp[q], av = ap[q], dv = bp[q];
    s += hv.x * av.x + hv.y * av.y + hv.z * av.z + hv.w * av.w;
    d += hv.x * dv.x + hv.y * dv.y + hv.z * dv.z + hv.w * dv.w;
  }
  es[idx] = s; ed[idx] = d;
}

// ------ layer-1 aggregation: one wave per dst, CSR, 2-pass softmax ---------
// lane covers t = lane + 64q (q=0..4); head of (lane,q) = 2q + (lane>>5)
__global__ __launch_bounds__(256) void agg1(const int* __restrict__ roff,
                                            const int* __restrict__ ssrc,
                                            const float* __restrict__ es,
                                            const float* __restrict__ ed,
                                            const float* __restrict__ h1,
                                            const float* __restrict__ b1,
                                            float* __restrict__ act) {
  int wid = (blockIdx.x * 256 + threadIdx.x) >> 6;
  if (wid >= N_NODES) return;
  const int lane = threadIdx.x & 63;
  const int n = wid;
  const int beg = roff[n], end = roff[n + 1];
  const int hb = lane >> 5;                 // 0 or 1
  float edv[5], m[5];
  #pragma unroll
  for (int q = 0; q < 5; q++) { edv[q] = ed[n * 10 + 2 * q + hb]; m[q] = -1e30f; }
  // pass 1: per-head segment max
  for (int j = beg; j < end; j++) {
    int src = ssrc[j];
    #pragma unroll
    for (int q = 0; q < 5; q++) {
      float a = es[src * 10 + 2 * q + hb] + edv[q];
      a = a > 0.f ? a : NEG_SLOPE * a;
      m[q] = fmaxf(m[q], a);
    }
  }
  // pass 2: exp-weighted gather-accumulate
  float acc[5] = {}; float d[5] = {};
  for (int j = beg; j < end; j++) {
    int src = ssrc[j];
    const float* hrow = h1 + (size_t)src * HC;
    #pragma unroll
    for (int q = 0; q < 5; q++) {
      float a = es[src * 10 + 2 * q + hb] + edv[q];
      a = a > 0.f ? a : NEG_SLOPE * a;
      float ex = expf(a - m[q]);
      acc[q] += hrow[lane + 64 * q] * ex;
      d[q] += ex;
    }
  }
  #pragma unroll
  for (int q = 0; q < 5; q++) {
    float v = acc[q] / (d[q] + 1e-16f) + b1[lane + 64 * q];
    v = v > 0.f ? v : expm1f(v);
    act[(size_t)n * HC + lane + 64 * q] = v;
  }
}

// ---------------- GEMM2: h2[N,32] = act[N,320] @ W2[320,32] ----------------
__global__ __launch_bounds__(256) void gemm2(const float* __restrict__ A,
                                             const float* __restrict__ W,
                                             float* __restrict__ Hout) {
  __shared__ float As[32][65];
  __shared__ float Bs[32][32];
  const int n0 = blockIdx.x * 64;
  const int tx = threadIdx.x;
  const int ty = threadIdx.y;
  const int tid = ty * 32 + tx;
  float acc[8] = {};
  for (int k0 = 0; k0 < HC; k0 += 32) {
    #pragma unroll
    for (int i = 0; i < 8; i++) {
      int idx = tid + 256 * i;
      int n = idx >> 5, k = idx & 31;
      int nn = n0 + n;
      As[k][n] = (nn < N_NODES) ? A[(size_t)nn * HC + k0 + k] : 0.f;
    }
    #pragma unroll
    for (int i = 0; i < 4; i++) {
      int idx = tid + 256 * i;
      int k = idx >> 5, j = idx & 31;
      Bs[k][j] = W[(size_t)(k0 + k) * OUT_CH + j];
    }
    __syncthreads();
    #pragma unroll
    for (int k = 0; k < 32; k++) {
      float b = Bs[k][tx];
      #pragma unroll
      for (int i = 0; i < 8; i++) acc[i] += As[k][ty + 8 * i] * b;
    }
    __syncthreads();
  }
  #pragma unroll
  for (int i = 0; i < 8; i++) {
    int n = n0 + ty + 8 * i;
    if (n < N_NODES) Hout[(size_t)n * OUT_CH + tx] = acc[i];
  }
}

// ---------------- e_src2/e_dst2 per node (H=1) -----------------------------
__global__ __launch_bounds__(256) void edot2(const float* __restrict__ h2,
                                             const float* __restrict__ a_src,
                                             const float* __restrict__ a_dst,
                                             float* __restrict__ es,
                                             float* __restrict__ ed) {
  int n = blockIdx.x * 256 + threadIdx.x;
  if (n >= N_NODES) return;
  const float4* hp = reinterpret_cast<const float4*>(h2 + (size_t)n * OUT_CH);
  const float4* ap = reinterpret_cast<const float4*>(a_src);
  const float4* bp = reinterpret_cast<const float4*>(a_dst);
  float s = 0.f, d = 0.f;
  #pragma unroll
  for (int q = 0; q < 8; q++) {
    float4 hv = hp[q], av = ap[q], dv = bp[q];
    s += hv.x * av.x + hv.y * av.y + hv.z * av.z + hv.w * av.w;
    d += hv.x * dv.x + hv.y * dv.y + hv.z * dv.z + hv.w * dv.w;
  }
  es[n] = s; ed[n] = d;
}

// ------ layer-2 aggregation: half-wave per dst, CSR, 2-pass, fused pool ----
__global__ __launch_bounds__(256) void agg2(const int* __restrict__ roff,
                                            const int* __restrict__ ssrc,
                                            const float* __restrict__ es,
                                            const float* __restrict__ ed,
                                            const float* __restrict__ h2,
                                            const float* __restrict__ b2,
                                            const int* __restrict__ batch,
                                            unsigned* __restrict__ pooled) {
  int n = (blockIdx.x * 256 + threadIdx.x) >> 5;
  if (n >= N_NODES) return;
  const int c = threadIdx.x & 31;
  const int beg = roff[n], end = roff[n + 1];
  const float edv = ed[n];
  float m = -1e30f;
  for (int j = beg; j < end; j++) {
    float a = es[ssrc[j]] + edv;
    a = a > 0.f ? a : NEG_SLOPE * a;
    m = fmaxf(m, a);
  }
  float acc = 0.f, d = 0.f;
  for (int j = beg; j < end; j++) {
    int src = ssrc[j];
    float a = es[src] + edv;
    a = a > 0.f ? a : NEG_SLOPE * a;
    float ex = expf(a - m);
    acc += h2[(size_t)src * OUT_CH + c] * ex;
    d += ex;
  }
  float v = acc / (d + 1e-16f) + b2[c];
  v = v > 0.f ? v : expm1f(v);
  atomicMax(&pooled[batch[n] * OUT_CH + c], fmap(v));
}

// -------- final: out[g,c] = relu(pooled[g,:] @ fc_w[:,c] + fc_b[c]) --------
__global__ __launch_bounds__(256) void final_k(const unsigned* __restrict__ pooled,
                                               const float* __restrict__ fc_w,
                                               const float* __restrict__ fc_b,
                                               float* __restrict__ out) {
  int idx = blockIdx.x * 256 + threadIdx.x;
  if (idx >= N_GRAPHS * OUT_CH) return;
  int g = idx >> 5, c = idx & 5 * 6 + 1;  // c = idx & 31
  c = idx & 31;
  float s = fc_b[c];
  #pragma unroll
  for (int k = 0; k < OUT_CH; k++) {
    unsigned u = pooled[g * OUT_CH + k];
    float p = (u == 0u) ? 0.f : funmap(u);
    s += p * fc_w[k * OUT_CH + c];
  }
  out[idx] = s > 0.f ? s : 0.f;
}

extern "C" void kernel_launch(void* const* d_in, const int* in_sizes, int n_in,
                              void* d_out, int out_size, void* d_ws, size_t ws_size,
                              hipStream_t stream) {
  const float* x      = (const float*)d_in[0];
  const int*   ei     = (const int*)d_in[1];
  const int*   batch  = (const int*)d_in[2];
  const float* W1     = (const float*)d_in[4];
  const float* a_src1 = (const float*)d_in[5];
  const float* a_dst1 = (const float*)d_in[6];
  const float* b1     = (const float*)d_in[7];
  const float* W2     = (const float*)d_in[8];
  const float* a_src2 = (const float*)d_in[9];
  const float* a_dst2 = (const float*)d_in[10];
  const float* b2     = (const float*)d_in[11];
  const float* fc_w   = (const float*)d_in[12];
  const float* fc_b   = (const float*)d_in[13];
  float* out = (float*)d_out;

  // ---- workspace layout (<= 136 MB) ----
  char* ws = (char*)d_ws;
  float* h1   = (float*)(ws);                 // 64 MB; h2 reuses after agg1
  float* act1 = (float*)(ws + 64000000);      // 64 MB
  char*  S    = ws + 128000000;               // ~7.9 MB small region
  int*   ssrc   = (int*)(S);                  // 3.2 MB
  int*   roff   = (int*)(S + 3200000);        // 200,004 B
  int*   deg    = (int*)(S + 3400064);        // 200,000 B
  int*   cursor = (int*)(S + 3600064);        // 200,000 B
  float* es1    = (float*)(S + 3800064);      // 2 MB
  float* ed1    = (float*)(S + 5800064);      // 2 MB
  int*   bsum   = (int*)(S + 7800064);        // 784 B
  unsigned* pooled = (unsigned*)(S + 7801600);// 64 KB
  float* h2  = (float*)(ws);                  // 6.4 MB (h1 dead after agg1)
  float* es2 = es1; float* ed2 = ed1;         // es1/ed1 dead after agg1

  // ---- CSR build (independent of features) ----
  hipMemsetAsync(deg, 0, (size_t)N_NODES * 4, stream);
  hipMemsetAsync(cursor, 0, (size_t)N_NODES * 4, stream);
  hist_k   <<<(N_EDGES + 255) / 256, 256, 0, stream>>>(ei, deg);
  scan_blk <<<NBLK_SCAN, 256, 0, stream>>>(deg, roff, bsum);
  scan_top <<<1, 256, 0, stream>>>(bsum);
  scan_add <<<NBLK_SCAN, 256, 0, stream>>>(roff, bsum);
  scatter_k<<<(N_EDGES + 255) / 256, 256, 0, stream>>>(ei, roff, cursor, ssrc);

  // ---- layer 1 ----
  gemm1<<<dim3(HC / 64, (N_NODES + 63) / 64), dim3(16, 16), 0, stream>>>(x, W1, h1);
  edot1<<<(N_NODES * HEADS + 255) / 256, 256, 0, stream>>>(h1, a_src1, a_dst1, es1, ed1);
  agg1 <<<(N_NODES * 64 + 255) / 256, 256, 0, stream>>>(roff, ssrc, es1, ed1, h1, b1, act1);

  // ---- layer 2 ----
  hipMemsetAsync(pooled, 0, (size_t)N_GRAPHS * OUT_CH * 4, stream);
  gemm2<<<dim3((N_NODES + 63) / 64), dim3(32, 8), 0, stream>>>(act1, W2, h2);
  edot2<<<(N_NODES + 255) / 256, 256, 0, stream>>>(h2, a_src2, a_dst2, es2, ed2);
  agg2 <<<(N_NODES * 32 + 255) / 256, 256, 0, stream>>>(roff, ssrc, es2, ed2, h2, b2, batch, pooled);
  final_k<<<(N_GRAPHS * OUT_CH + 255) / 256, 256, 0, stream>>>(pooled, fc_w, fc_b, out);
}

// Round 3
// 474.754 us; speedup vs baseline: 3.7261x; 1.2333x over previous
//
#include <hip/hip_runtime.h>

#define N_NODES 50000
#define N_EDGES 800000
#define IN_CH   128
#define OUT_CH  32
#define HEADS   10
#define HC      320           // HEADS*OUT_CH
#define N_GRAPHS 512
#define NEG_SLOPE 0.2f
#define NBLK_SCAN 196         // ceil(50000/256)

// ---- order-preserving float<->uint map for atomicMax-based segment_max ----
__device__ __forceinline__ unsigned fmap(float f) {
  unsigned u = __float_as_uint(f);
  return (u & 0x80000000u) ? ~u : (u | 0x80000000u);
}
__device__ __forceinline__ float funmap(unsigned u) {
  u = (u & 0x80000000u) ? (u ^ 0x80000000u) : ~u;
  return __uint_as_float(u);
}
__device__ __forceinline__ float leaky(float a) {
  return a > 0.f ? a : NEG_SLOPE * a;
}

// ============================ CSR construction =============================
__global__ __launch_bounds__(256) void hist_k(const int* __restrict__ ei,
                                              int* __restrict__ deg) {
  int e = blockIdx.x * 256 + threadIdx.x;
  if (e < N_EDGES) atomicAdd(&deg[ei[N_EDGES + e]], 1);
}

__global__ __launch_bounds__(256) void scan_blk(const int* __restrict__ deg,
                                                int* __restrict__ roff,
                                                int* __restrict__ bsum) {
  __shared__ int s[256];
  int i = blockIdx.x * 256 + threadIdx.x;
  int v = (i < N_NODES) ? deg[i] : 0;
  s[threadIdx.x] = v;
  __syncthreads();
  #pragma unroll
  for (int o = 1; o < 256; o <<= 1) {
    int t = (threadIdx.x >= o) ? s[threadIdx.x - o] : 0;
    __syncthreads();
    s[threadIdx.x] += t;
    __syncthreads();
  }
  if (i < N_NODES) roff[i] = s[threadIdx.x] - v;   // exclusive
  if (threadIdx.x == 255) bsum[blockIdx.x] = s[255];
}

__global__ __launch_bounds__(256) void scan_top(int* __restrict__ bsum) {
  __shared__ int s[256];
  int i = threadIdx.x;
  int v = (i < NBLK_SCAN) ? bsum[i] : 0;
  s[i] = v;
  __syncthreads();
  #pragma unroll
  for (int o = 1; o < 256; o <<= 1) {
    int t = (i >= o) ? s[i - o] : 0;
    __syncthreads();
    s[i] += t;
    __syncthreads();
  }
  if (i < NBLK_SCAN) bsum[i] = s[i] - v;           // exclusive
}

__global__ __launch_bounds__(256) void scan_add(int* __restrict__ roff,
                                                const int* __restrict__ bsum) {
  int i = blockIdx.x * 256 + threadIdx.x;
  if (i < N_NODES) roff[i] += bsum[blockIdx.x];
  if (i == 0) roff[N_NODES] = N_EDGES;
}

__global__ __launch_bounds__(256) void scatter_k(const int* __restrict__ ei,
                                                 const int* __restrict__ roff,
                                                 int* __restrict__ cursor,
                                                 int* __restrict__ ssrc) {
  int e = blockIdx.x * 256 + threadIdx.x;
  if (e >= N_EDGES) return;
  int dst = ei[N_EDGES + e];
  int pos = roff[dst] + atomicAdd(&cursor[dst], 1);
  ssrc[pos] = ei[e];
}

// ---------------- GEMM1: h1[N,320] = x[N,128] @ W1[128,320] ----------------
__global__ __launch_bounds__(256) void gemm1(const float* __restrict__ X,
                                             const float* __restrict__ W,
                                             float* __restrict__ Hout) {
  __shared__ float As[32][65];
  __shared__ float Bs[32][64];
  const int n0 = blockIdx.y * 64;
  const int j0 = blockIdx.x * 64;
  const int tid = threadIdx.y * 16 + threadIdx.x;
  float acc[4][4] = {};
  for (int k0 = 0; k0 < IN_CH; k0 += 32) {
    #pragma unroll
    for (int i = 0; i < 8; i++) {
      int idx = tid + 256 * i;
      int n = idx >> 5, k = idx & 31;
      int nn = n0 + n;
      As[k][n] = (nn < N_NODES) ? X[(size_t)nn * IN_CH + k0 + k] : 0.f;
    }
    #pragma unroll
    for (int i = 0; i < 8; i++) {
      int idx = tid + 256 * i;
      int k = idx >> 6, j = idx & 63;
      Bs[k][j] = W[(size_t)(k0 + k) * HC + j0 + j];
    }
    __syncthreads();
    #pragma unroll
    for (int k = 0; k < 32; k++) {
      float a[4], b[4];
      #pragma unroll
      for (int i = 0; i < 4; i++) a[i] = As[k][threadIdx.y + 16 * i];
      #pragma unroll
      for (int j = 0; j < 4; j++) b[j] = Bs[k][threadIdx.x + 16 * j];
      #pragma unroll
      for (int i = 0; i < 4; i++)
        #pragma unroll
        for (int j = 0; j < 4; j++) acc[i][j] += a[i] * b[j];
    }
    __syncthreads();
  }
  #pragma unroll
  for (int i = 0; i < 4; i++) {
    int n = n0 + threadIdx.y + 16 * i;
    if (n >= N_NODES) continue;
    #pragma unroll
    for (int j = 0; j < 4; j++)
      Hout[(size_t)n * HC + j0 + threadIdx.x + 16 * j] = acc[i][j];
  }
}

// -------- e_src/e_dst per (node, head): dot(h1[n,h,:], a_src[h,:]) ---------
__global__ __launch_bounds__(256) void edot1(const float* __restrict__ h1,
                                             const float* __restrict__ a_src,
                                             const float* __restrict__ a_dst,
                                             float* __restrict__ es,
                                             float* __restrict__ ed) {
  int idx = blockIdx.x * 256 + threadIdx.x;
  if (idx >= N_NODES * HEADS) return;
  int n = idx / HEADS, h = idx - n * HEADS;
  const float4* hp = reinterpret_cast<const float4*>(h1 + (size_t)n * HC + h * OUT_CH);
  const float4* ap = reinterpret_cast<const float4*>(a_src + h * OUT_CH);
  const float4* bp = reinterpret_cast<const float4*>(a_dst + h * OUT_CH);
  float s = 0.f, d = 0.f;
  #pragma unroll
  for (int q = 0; q < 8; q++) {
    float4 hv = hp[q], av = ap[q], dv = bp[q];
    s += hv.x * av.x + hv.y * av.y + hv.z * av.z + hv.w * av.w;
    d += hv.x * dv.x + hv.y * dv.y + hv.z * dv.z + hv.w * dv.w;
  }
  es[idx] = s; ed[idx] = d;
}

// ------ layer-1 aggregation: one wave per dst node, wave-coop softmax ------
// lane covers cols t = lane + 64q (q=0..4); head of (lane,q) = 2q + (lane>>5)
__global__ __launch_bounds__(256) void agg1(const int* __restrict__ roff,
                                            const int* __restrict__ ssrc,
                                            const float* __restrict__ es,
                                            const float* __restrict__ ed,
                                            const float* __restrict__ h1,
                                            const float* __restrict__ b1,
                                            float* __restrict__ act) {
  __shared__ float lds[4][64][11];   // [wave][edge][0..9]=ex, [10]=src bits
  const int n = (blockIdx.x * 256 + threadIdx.x) >> 6;
  if (n >= N_NODES) return;
  const int wslot = threadIdx.x >> 6;
  const int lane = threadIdx.x & 63;
  const int hb = lane >> 5;                 // 0 or 1
  const int beg = roff[n];
  const int deg = roff[n + 1] - beg;

  if (deg == 0) {
    #pragma unroll
    for (int q = 0; q < 5; q++) {
      float v = b1[lane + 64 * q];
      v = v > 0.f ? v : expm1f(v);
      act[(size_t)n * HC + lane + 64 * q] = v;
    }
    return;
  }

  float acc[5] = {};

  if (deg <= 64) {
    // ---- phase 1: lane e owns edge e; compute 10 alphas in registers ----
    const int active = (lane < deg);
    const int src = ssrc[beg + (active ? lane : 0)];
    float a[10];
    #pragma unroll
    for (int p = 0; p < 5; p++) {
      float2 edp = *reinterpret_cast<const float2*>(ed + n * 10 + 2 * p);
      float2 esp = *reinterpret_cast<const float2*>(es + src * 10 + 2 * p);
      a[2 * p]     = active ? leaky(esp.x + edp.x) : -1e30f;
      a[2 * p + 1] = active ? leaky(esp.y + edp.y) : -1e30f;
    }
    // per-head wave max
    float m[10];
    #pragma unroll
    for (int h = 0; h < 10; h++) m[h] = a[h];
    #pragma unroll
    for (int o = 1; o < 64; o <<= 1)
      #pragma unroll
      for (int h = 0; h < 10; h++) m[h] = fmaxf(m[h], __shfl_xor(m[h], o));
    // exp (exactly deg*10 real exps), park in LDS; per-head wave denom
    float d[10];
    #pragma unroll
    for (int h = 0; h < 10; h++) {
      float ex = expf(a[h] - m[h]);        // 0 for inactive lanes
      lds[wslot][lane][h] = ex;
      d[h] = ex;
    }
    lds[wslot][lane][10] = __int_as_float(src);
    #pragma unroll
    for (int o = 1; o < 64; o <<= 1)
      #pragma unroll
      for (int h = 0; h < 10; h++) d[h] += __shfl_xor(d[h], o);

    // ---- phase 2: gather h1 rows weighted by LDS-broadcast coefs ----
    for (int j = 0; j < deg; j++) {
      int sj = __float_as_int(lds[wslot][j][10]);
      const float* hrow = h1 + (size_t)sj * HC + lane;
      #pragma unroll
      for (int q = 0; q < 5; q++)
        acc[q] = fmaf(hrow[64 * q], lds[wslot][j][2 * q + hb], acc[q]);
    }
    #pragma unroll
    for (int q = 0; q < 5; q++) {
      float v = acc[q] / (d[2 * q + hb] + 1e-16f) + b1[lane + 64 * q];
      v = v > 0.f ? v : expm1f(v);
      act[(size_t)n * HC + lane + 64 * q] = v;
    }
  } else {
    // ---- slow fallback (deg > 64): per-lane redundant 2-pass ----
    float edv[5], m2[5];
    #pragma unroll
    for (int q = 0; q < 5; q++) { edv[q] = ed[n * 10 + 2 * q + hb]; m2[q] = -1e30f; }
    for (int j = beg; j < beg + deg; j++) {
      int src = ssrc[j];
      #pragma unroll
      for (int q = 0; q < 5; q++)
        m2[q] = fmaxf(m2[q], leaky(es[src * 10 + 2 * q + hb] + edv[q]));
    }
    float d2[5] = {};
    for (int j = beg; j < beg + deg; j++) {
      int src = ssrc[j];
      const float* hrow = h1 + (size_t)src * HC + lane;
      #pragma unroll
      for (int q = 0; q < 5; q++) {
        float ex = expf(leaky(es[src * 10 + 2 * q + hb] + edv[q]) - m2[q]);
        acc[q] = fmaf(hrow[64 * q], ex, acc[q]);
        d2[q] += ex;
      }
    }
    #pragma unroll
    for (int q = 0; q < 5; q++) {
      float v = acc[q] / (d2[q] + 1e-16f) + b1[lane + 64 * q];
      v = v > 0.f ? v : expm1f(v);
      act[(size_t)n * HC + lane + 64 * q] = v;
    }
  }
}

// ---------------- GEMM2: h2[N,32] = act[N,320] @ W2[320,32] ----------------
__global__ __launch_bounds__(256) void gemm2(const float* __restrict__ A,
                                             const float* __restrict__ W,
                                             float* __restrict__ Hout) {
  __shared__ float As[32][65];
  __shared__ float Bs[32][32];
  const int n0 = blockIdx.x * 64;
  const int tx = threadIdx.x;
  const int ty = threadIdx.y;
  const int tid = ty * 32 + tx;
  float acc[8] = {};
  for (int k0 = 0; k0 < HC; k0 += 32) {
    #pragma unroll
    for (int i = 0; i < 8; i++) {
      int idx = tid + 256 * i;
      int n = idx >> 5, k = idx & 31;
      int nn = n0 + n;
      As[k][n] = (nn < N_NODES) ? A[(size_t)nn * HC + k0 + k] : 0.f;
    }
    #pragma unroll
    for (int i = 0; i < 4; i++) {
      int idx = tid + 256 * i;
      int k = idx >> 5, j = idx & 31;
      Bs[k][j] = W[(size_t)(k0 + k) * OUT_CH + j];
    }
    __syncthreads();
    #pragma unroll
    for (int k = 0; k < 32; k++) {
      float b = Bs[k][tx];
      #pragma unroll
      for (int i = 0; i < 8; i++) acc[i] += As[k][ty + 8 * i] * b;
    }
    __syncthreads();
  }
  #pragma unroll
  for (int i = 0; i < 8; i++) {
    int n = n0 + ty + 8 * i;
    if (n < N_NODES) Hout[(size_t)n * OUT_CH + tx] = acc[i];
  }
}

// ---------------- e_src2/e_dst2 per node (H=1) -----------------------------
__global__ __launch_bounds__(256) void edot2(const float* __restrict__ h2,
                                             const float* __restrict__ a_src,
                                             const float* __restrict__ a_dst,
                                             float* __restrict__ es,
                                             float* __restrict__ ed) {
  int n = blockIdx.x * 256 + threadIdx.x;
  if (n >= N_NODES) return;
  const float4* hp = reinterpret_cast<const float4*>(h2 + (size_t)n * OUT_CH);
  const float4* ap = reinterpret_cast<const float4*>(a_src);
  const float4* bp = reinterpret_cast<const float4*>(a_dst);
  float s = 0.f, d = 0.f;
  #pragma unroll
  for (int q = 0; q < 8; q++) {
    float4 hv = hp[q], av = ap[q], dv = bp[q];
    s += hv.x * av.x + hv.y * av.y + hv.z * av.z + hv.w * av.w;
    d += hv.x * dv.x + hv.y * dv.y + hv.z * dv.z + hv.w * dv.w;
  }
  es[n] = s; ed[n] = d;
}

// ------ layer-2 aggregation: one wave per node, 2 edges/iter, fused pool ---
__global__ __launch_bounds__(256) void agg2(const int* __restrict__ roff,
                                            const int* __restrict__ ssrc,
                                            const float* __restrict__ es,
                                            const float* __restrict__ ed,
                                            const float* __restrict__ h2,
                                            const float* __restrict__ b2,
                                            const int* __restrict__ batch,
                                            unsigned* __restrict__ pooled) {
  __shared__ float lds[4][64][2];    // [wave][edge][0]=ex, [1]=src bits
  const int n = (blockIdx.x * 256 + threadIdx.x) >> 6;
  if (n >= N_NODES) return;
  const int wslot = threadIdx.x >> 6;
  const int lane = threadIdx.x & 63;
  const int c = lane & 31;
  const int hb = lane >> 5;
  const int beg = roff[n];
  const int deg = roff[n + 1] - beg;
  const int g = batch[n];

  if (deg == 0) {
    if (lane < 32) {
      float v = b2[c];
      v = v > 0.f ? v : expm1f(v);
      atomicMax(&pooled[g * OUT_CH + c], fmap(v));
    }
    return;
  }

  float acc = 0.f, dtot;

  if (deg <= 64) {
    const int active = (lane < deg);
    const int src = ssrc[beg + (active ? lane : 0)];
    const float edv = ed[n];
    float a = active ? leaky(es[src] + edv) : -1e30f;
    float m = a;
    #pragma unroll
    for (int o = 1; o < 64; o <<= 1) m = fmaxf(m, __shfl_xor(m, o));
    float ex = expf(a - m);
    float d = ex;
    #pragma unroll
    for (int o = 1; o < 64; o <<= 1) d += __shfl_xor(d, o);
    dtot = d;
    lds[wslot][lane][0] = ex;
    lds[wslot][lane][1] = __int_as_float(src);
    for (int j = hb; j < deg; j += 2) {
      int sj = __float_as_int(lds[wslot][j][1]);
      acc = fmaf(h2[(size_t)sj * OUT_CH + c], lds[wslot][j][0], acc);
    }
  } else {
    // slow fallback: redundant per-lane scalars
    const float edv = ed[n];
    float m = -1e30f;
    for (int j = beg; j < beg + deg; j++)
      m = fmaxf(m, leaky(es[ssrc[j]] + edv));
    float d = 0.f;
    for (int j = beg + hb; j < beg + deg; j += 2) {
      int src = ssrc[j];
      float ex = expf(leaky(es[src] + edv) - m);
      acc = fmaf(h2[(size_t)src * OUT_CH + c], ex, acc);
      d += ex;
    }
    d += __shfl_xor(d, 32);
    dtot = d;
  }

  acc += __shfl_xor(acc, 32);
  if (lane < 32) {
    float v = acc / (dtot + 1e-16f) + b2[c];
    v = v > 0.f ? v : expm1f(v);
    atomicMax(&pooled[g * OUT_CH + c], fmap(v));
  }
}

// -------- final: out[g,c] = relu(pooled[g,:] @ fc_w[:,c] + fc_b[c]) --------
__global__ __launch_bounds__(256) void final_k(const unsigned* __restrict__ pooled,
                                               const float* __restrict__ fc_w,
                                               const float* __restrict__ fc_b,
                                               float* __restrict__ out) {
  int idx = blockIdx.x * 256 + threadIdx.x;
  if (idx >= N_GRAPHS * OUT_CH) return;
  int g = idx >> 5, c = idx & 31;
  float s = fc_b[c];
  #pragma unroll
  for (int k = 0; k < OUT_CH; k++) {
    unsigned u = pooled[g * OUT_CH + k];
    float p = (u == 0u) ? 0.f : funmap(u);
    s += p * fc_w[k * OUT_CH + c];
  }
  out[idx] = s > 0.f ? s : 0.f;
}

extern "C" void kernel_launch(void* const* d_in, const int* in_sizes, int n_in,
                              void* d_out, int out_size, void* d_ws, size_t ws_size,
                              hipStream_t stream) {
  const float* x      = (const float*)d_in[0];
  const int*   ei     = (const int*)d_in[1];
  const int*   batch  = (const int*)d_in[2];
  const float* W1     = (const float*)d_in[4];
  const float* a_src1 = (const float*)d_in[5];
  const float* a_dst1 = (const float*)d_in[6];
  const float* b1     = (const float*)d_in[7];
  const float* W2     = (const float*)d_in[8];
  const float* a_src2 = (const float*)d_in[9];
  const float* a_dst2 = (const float*)d_in[10];
  const float* b2     = (const float*)d_in[11];
  const float* fc_w   = (const float*)d_in[12];
  const float* fc_b   = (const float*)d_in[13];
  float* out = (float*)d_out;

  // ---- workspace layout (<= 136 MB) ----
  char* ws = (char*)d_ws;
  float* h1   = (float*)(ws);                 // 64 MB; h2 reuses after agg1
  float* act1 = (float*)(ws + 64000000);      // 64 MB
  char*  S    = ws + 128000000;               // ~7.9 MB small region
  int*   ssrc   = (int*)(S);                  // 3.2 MB
  int*   roff   = (int*)(S + 3200000);        // 200,004 B
  int*   deg    = (int*)(S + 3400064);        // 200,000 B
  int*   cursor = (int*)(S + 3600064);        // 200,000 B
  float* es1    = (float*)(S + 3800064);      // 2 MB
  float* ed1    = (float*)(S + 5800064);      // 2 MB
  int*   bsum   = (int*)(S + 7800064);        // 784 B
  unsigned* pooled = (unsigned*)(S + 7801600);// 64 KB
  float* h2  = (float*)(ws);                  // 6.4 MB (h1 dead after agg1)
  float* es2 = es1; float* ed2 = ed1;         // es1/ed1 dead after agg1

  // ---- CSR build ----
  hipMemsetAsync(deg, 0, (size_t)N_NODES * 4, stream);
  hipMemsetAsync(cursor, 0, (size_t)N_NODES * 4, stream);
  hist_k   <<<(N_EDGES + 255) / 256, 256, 0, stream>>>(ei, deg);
  scan_blk <<<NBLK_SCAN, 256, 0, stream>>>(deg, roff, bsum);
  scan_top <<<1, 256, 0, stream>>>(bsum);
  scan_add <<<NBLK_SCAN, 256, 0, stream>>>(roff, bsum);
  scatter_k<<<(N_EDGES + 255) / 256, 256, 0, stream>>>(ei, roff, cursor, ssrc);

  // ---- layer 1 ----
  gemm1<<<dim3(HC / 64, (N_NODES + 63) / 64), dim3(16, 16), 0, stream>>>(x, W1, h1);
  edot1<<<(N_NODES * HEADS + 255) / 256, 256, 0, stream>>>(h1, a_src1, a_dst1, es1, ed1);
  agg1 <<<(N_NODES * 64 + 255) / 256, 256, 0, stream>>>(roff, ssrc, es1, ed1, h1, b1, act1);

  // ---- layer 2 ----
  hipMemsetAsync(pooled, 0, (size_t)N_GRAPHS * OUT_CH * 4, stream);
  gemm2<<<dim3((N_NODES + 63) / 64), dim3(32, 8), 0, stream>>>(act1, W2, h2);
  edot2<<<(N_NODES + 255) / 256, 256, 0, stream>>>(h2, a_src2, a_dst2, es2, ed2);
  agg2 <<<(N_NODES * 64 + 255) / 256, 256, 0, stream>>>(roff, ssrc, es2, ed2, h2, b2, batch, pooled);
  final_k<<<(N_GRAPHS * OUT_CH + 255) / 256, 256, 0, stream>>>(pooled, fc_w, fc_b, out);
}

// Round 7
// 470.268 us; speedup vs baseline: 3.7616x; 1.0095x over previous
//
#include <hip/hip_runtime.h>

#define N_NODES 50000
#define N_EDGES 800000
#define IN_CH   128
#define OUT_CH  32
#define HEADS   10
#define HC      320           // HEADS*OUT_CH
#define N_GRAPHS 512
#define NEG_SLOPE 0.2f
#define NBLK_SCAN 196         // ceil(50000/256)

// ---- order-preserving float<->uint map for atomicMax-based segment_max ----
__device__ __forceinline__ unsigned fmap(float f) {
  unsigned u = __float_as_uint(f);
  return (u & 0x80000000u) ? ~u : (u | 0x80000000u);
}
__device__ __forceinline__ float funmap(unsigned u) {
  u = (u & 0x80000000u) ? (u ^ 0x80000000u) : ~u;
  return __uint_as_float(u);
}
__device__ __forceinline__ float leaky(float a) {
  return a > 0.f ? a : NEG_SLOPE * a;
}

// ============================ CSR construction =============================
__global__ __launch_bounds__(256) void hist_k(const int* __restrict__ ei,
                                              int* __restrict__ deg) {
  int e = blockIdx.x * 256 + threadIdx.x;
  if (e < N_EDGES) atomicAdd(&deg[ei[N_EDGES + e]], 1);
}

__global__ __launch_bounds__(256) void scan_blk(const int* __restrict__ deg,
                                                int* __restrict__ roff,
                                                int* __restrict__ bsum) {
  __shared__ int s[256];
  int i = blockIdx.x * 256 + threadIdx.x;
  int v = (i < N_NODES) ? deg[i] : 0;
  s[threadIdx.x] = v;
  __syncthreads();
  #pragma unroll
  for (int o = 1; o < 256; o <<= 1) {
    int t = (threadIdx.x >= o) ? s[threadIdx.x - o] : 0;
    __syncthreads();
    s[threadIdx.x] += t;
    __syncthreads();
  }
  if (i < N_NODES) roff[i] = s[threadIdx.x] - v;   // exclusive
  if (threadIdx.x == 255) bsum[blockIdx.x] = s[255];
}

__global__ __launch_bounds__(256) void scan_top(int* __restrict__ bsum) {
  __shared__ int s[256];
  int i = threadIdx.x;
  int v = (i < NBLK_SCAN) ? bsum[i] : 0;
  s[i] = v;
  __syncthreads();
  #pragma unroll
  for (int o = 1; o < 256; o <<= 1) {
    int t = (i >= o) ? s[i - o] : 0;
    __syncthreads();
    s[i] += t;
    __syncthreads();
  }
  if (i < NBLK_SCAN) bsum[i] = s[i] - v;           // exclusive
}

__global__ __launch_bounds__(256) void scan_add(int* __restrict__ roff,
                                                const int* __restrict__ bsum) {
  int i = blockIdx.x * 256 + threadIdx.x;
  if (i < N_NODES) roff[i] += bsum[blockIdx.x];
  if (i == 0) roff[N_NODES] = N_EDGES;
}

__global__ __launch_bounds__(256) void scatter_k(const int* __restrict__ ei,
                                                 const int* __restrict__ roff,
                                                 int* __restrict__ cursor,
                                                 int* __restrict__ ssrc) {
  int e = blockIdx.x * 256 + threadIdx.x;
  if (e >= N_EDGES) return;
  int dst = ei[N_EDGES + e];
  int pos = roff[dst] + atomicAdd(&cursor[dst], 1);
  ssrc[pos] = ei[e];
}

// ---------------- GEMM1: h1[N,320] = x[N,128] @ W1[128,320] ----------------
__global__ __launch_bounds__(256) void gemm1(const float* __restrict__ X,
                                             const float* __restrict__ W,
                                             float* __restrict__ Hout) {
  __shared__ float As[32][65];
  __shared__ float Bs[32][64];
  const int n0 = blockIdx.y * 64;
  const int j0 = blockIdx.x * 64;
  const int tid = threadIdx.y * 16 + threadIdx.x;
  float acc[4][4] = {};
  for (int k0 = 0; k0 < IN_CH; k0 += 32) {
    #pragma unroll
    for (int i = 0; i < 8; i++) {
      int idx = tid + 256 * i;
      int n = idx >> 5, k = idx & 31;
      int nn = n0 + n;
      As[k][n] = (nn < N_NODES) ? X[(size_t)nn * IN_CH + k0 + k] : 0.f;
    }
    #pragma unroll
    for (int i = 0; i < 8; i++) {
      int idx = tid + 256 * i;
      int k = idx >> 6, j = idx & 63;
      Bs[k][j] = W[(size_t)(k0 + k) * HC + j0 + j];
    }
    __syncthreads();
    #pragma unroll
    for (int k = 0; k < 32; k++) {
      float a[4], b[4];
      #pragma unroll
      for (int i = 0; i < 4; i++) a[i] = As[k][threadIdx.y + 16 * i];
      #pragma unroll
      for (int j = 0; j < 4; j++) b[j] = Bs[k][threadIdx.x + 16 * j];
      #pragma unroll
      for (int i = 0; i < 4; i++)
        #pragma unroll
        for (int j = 0; j < 4; j++) acc[i][j] += a[i] * b[j];
    }
    __syncthreads();
  }
  #pragma unroll
  for (int i = 0; i < 4; i++) {
    int n = n0 + threadIdx.y + 16 * i;
    if (n >= N_NODES) continue;
    #pragma unroll
    for (int j = 0; j < 4; j++)
      Hout[(size_t)n * HC + j0 + threadIdx.x + 16 * j] = acc[i][j];
  }
}

// -------- e_src/e_dst per (node, head): dot(h1[n,h,:], a_src[h,:]) ---------
__global__ __launch_bounds__(256) void edot1(const float* __restrict__ h1,
                                             const float* __restrict__ a_src,
                                             const float* __restrict__ a_dst,
                                             float* __restrict__ es,
                                             float* __restrict__ ed) {
  int idx = blockIdx.x * 256 + threadIdx.x;
  if (idx >= N_NODES * HEADS) return;
  int n = idx / HEADS, h = idx - n * HEADS;
  const float4* hp = reinterpret_cast<const float4*>(h1 + (size_t)n * HC + h * OUT_CH);
  const float4* ap = reinterpret_cast<const float4*>(a_src + h * OUT_CH);
  const float4* bp = reinterpret_cast<const float4*>(a_dst + h * OUT_CH);
  float s = 0.f, d = 0.f;
  #pragma unroll
  for (int q = 0; q < 8; q++) {
    float4 hv = hp[q], av = ap[q], dv = bp[q];
    s += hv.x * av.x + hv.y * av.y + hv.z * av.z + hv.w * av.w;
    d += hv.x * dv.x + hv.y * dv.y + hv.z * dv.z + hv.w * dv.w;
  }
  es[idx] = s; ed[idx] = d;
}

// ------ layer-1 aggregation: one wave per dst node, wave-coop softmax ------
// lane covers cols t = lane + 64q (q=0..4); head of (lane,q) = 2q + (lane>>5)
__global__ __launch_bounds__(256) void agg1(const int* __restrict__ roff,
                                            const int* __restrict__ ssrc,
                                            const float* __restrict__ es,
                                            const float* __restrict__ ed,
                                            const float* __restrict__ h1,
                                            const float* __restrict__ b1,
                                            float* __restrict__ act) {
  __shared__ float lds[4][64][11];   // [wave][edge][0..9]=ex, [10]=src bits
  const int n = (blockIdx.x * 256 + threadIdx.x) >> 6;
  if (n >= N_NODES) return;
  const int wslot = threadIdx.x >> 6;
  const int lane = threadIdx.x & 63;
  const int hb = lane >> 5;                 // 0 or 1
  const int beg = roff[n];
  const int deg = roff[n + 1] - beg;

  if (deg == 0) {
    #pragma unroll
    for (int q = 0; q < 5; q++) {
      float v = b1[lane + 64 * q];
      v = v > 0.f ? v : expm1f(v);
      act[(size_t)n * HC + lane + 64 * q] = v;
    }
    return;
  }

  float acc[5] = {};

  if (deg <= 64) {
    // ---- phase 1: lane e owns edge e; compute 10 alphas in registers ----
    const int active = (lane < deg);
    const int src = ssrc[beg + (active ? lane : 0)];
    float a[10];
    #pragma unroll
    for (int p = 0; p < 5; p++) {
      float2 edp = *reinterpret_cast<const float2*>(ed + n * 10 + 2 * p);
      float2 esp = *reinterpret_cast<const float2*>(es + src * 10 + 2 * p);
      a[2 * p]     = active ? leaky(esp.x + edp.x) : -1e30f;
      a[2 * p + 1] = active ? leaky(esp.y + edp.y) : -1e30f;
    }
    // per-head wave max
    float m[10];
    #pragma unroll
    for (int h = 0; h < 10; h++) m[h] = a[h];
    #pragma unroll
    for (int o = 1; o < 64; o <<= 1)
      #pragma unroll
      for (int h = 0; h < 10; h++) m[h] = fmaxf(m[h], __shfl_xor(m[h], o));
    // exp (exactly deg*10 real exps), park in LDS; per-head wave denom
    float d[10];
    #pragma unroll
    for (int h = 0; h < 10; h++) {
      float ex = expf(a[h] - m[h]);        // 0 for inactive lanes
      lds[wslot][lane][h] = ex;
      d[h] = ex;
    }
    lds[wslot][lane][10] = __int_as_float(src);
    #pragma unroll
    for (int o = 1; o < 64; o <<= 1)
      #pragma unroll
      for (int h = 0; h < 10; h++) d[h] += __shfl_xor(d[h], o);

    // ---- phase 2: gather h1 rows weighted by LDS-broadcast coefs ----
    // 4-edge unroll: 20 independent global loads in flight per wave.
    int j = 0;
    for (; j + 4 <= deg; j += 4) {
      int s0 = __float_as_int(lds[wslot][j + 0][10]);
      int s1 = __float_as_int(lds[wslot][j + 1][10]);
      int s2 = __float_as_int(lds[wslot][j + 2][10]);
      int s3 = __float_as_int(lds[wslot][j + 3][10]);
      const float* __restrict__ r0 = h1 + (size_t)s0 * HC + lane;
      const float* __restrict__ r1 = h1 + (size_t)s1 * HC + lane;
      const float* __restrict__ r2 = h1 + (size_t)s2 * HC + lane;
      const float* __restrict__ r3 = h1 + (size_t)s3 * HC + lane;
      float v0[5], v1[5], v2[5], v3[5];
      #pragma unroll
      for (int q = 0; q < 5; q++) v0[q] = r0[64 * q];
      #pragma unroll
      for (int q = 0; q < 5; q++) v1[q] = r1[64 * q];
      #pragma unroll
      for (int q = 0; q < 5; q++) v2[q] = r2[64 * q];
      #pragma unroll
      for (int q = 0; q < 5; q++) v3[q] = r3[64 * q];
      float c0[5], c1[5], c2[5], c3[5];
      #pragma unroll
      for (int q = 0; q < 5; q++) {
        c0[q] = lds[wslot][j + 0][2 * q + hb];
        c1[q] = lds[wslot][j + 1][2 * q + hb];
        c2[q] = lds[wslot][j + 2][2 * q + hb];
        c3[q] = lds[wslot][j + 3][2 * q + hb];
      }
      #pragma unroll
      for (int q = 0; q < 5; q++) {
        acc[q] = fmaf(v0[q], c0[q], acc[q]);
        acc[q] = fmaf(v1[q], c1[q], acc[q]);
        acc[q] = fmaf(v2[q], c2[q], acc[q]);
        acc[q] = fmaf(v3[q], c3[q], acc[q]);
      }
    }
    for (; j < deg; j++) {
      int sj = __float_as_int(lds[wslot][j][10]);
      const float* __restrict__ hrow = h1 + (size_t)sj * HC + lane;
      #pragma unroll
      for (int q = 0; q < 5; q++)
        acc[q] = fmaf(hrow[64 * q], lds[wslot][j][2 * q + hb], acc[q]);
    }
    #pragma unroll
    for (int q = 0; q < 5; q++) {
      float v = acc[q] / (d[2 * q + hb] + 1e-16f) + b1[lane + 64 * q];
      v = v > 0.f ? v : expm1f(v);
      act[(size_t)n * HC + lane + 64 * q] = v;
    }
  } else {
    // ---- slow fallback (deg > 64): per-lane redundant 2-pass ----
    float edv[5], m2[5];
    #pragma unroll
    for (int q = 0; q < 5; q++) { edv[q] = ed[n * 10 + 2 * q + hb]; m2[q] = -1e30f; }
    for (int j = beg; j < beg + deg; j++) {
      int src = ssrc[j];
      #pragma unroll
      for (int q = 0; q < 5; q++)
        m2[q] = fmaxf(m2[q], leaky(es[src * 10 + 2 * q + hb] + edv[q]));
    }
    float d2[5] = {};
    for (int j = beg; j < beg + deg; j++) {
      int src = ssrc[j];
      const float* hrow = h1 + (size_t)src * HC + lane;
      #pragma unroll
      for (int q = 0; q < 5; q++) {
        float ex = expf(leaky(es[src * 10 + 2 * q + hb] + edv[q]) - m2[q]);
        acc[q] = fmaf(hrow[64 * q], ex, acc[q]);
        d2[q] += ex;
      }
    }
    #pragma unroll
    for (int q = 0; q < 5; q++) {
      float v = acc[q] / (d2[q] + 1e-16f) + b1[lane + 64 * q];
      v = v > 0.f ? v : expm1f(v);
      act[(size_t)n * HC + lane + 64 * q] = v;
    }
  }
}

// ---------------- GEMM2: h2[N,32] = act[N,320] @ W2[320,32] ----------------
__global__ __launch_bounds__(256) void gemm2(const float* __restrict__ A,
                                             const float* __restrict__ W,
                                             float* __restrict__ Hout) {
  __shared__ float As[32][65];
  __shared__ float Bs[32][32];
  const int n0 = blockIdx.x * 64;
  const int tx = threadIdx.x;
  const int ty = threadIdx.y;
  const int tid = ty * 32 + tx;
  float acc[8] = {};
  for (int k0 = 0; k0 < HC; k0 += 32) {
    #pragma unroll
    for (int i = 0; i < 8; i++) {
      int idx = tid + 256 * i;
      int n = idx >> 5, k = idx & 31;
      int nn = n0 + n;
      As[k][n] = (nn < N_NODES) ? A[(size_t)nn * HC + k0 + k] : 0.f;
    }
    #pragma unroll
    for (int i = 0; i < 4; i++) {
      int idx = tid + 256 * i;
      int k = idx >> 5, j = idx & 31;
      Bs[k][j] = W[(size_t)(k0 + k) * OUT_CH + j];
    }
    __syncthreads();
    #pragma unroll
    for (int k = 0; k < 32; k++) {
      float b = Bs[k][tx];
      #pragma unroll
      for (int i = 0; i < 8; i++) acc[i] += As[k][ty + 8 * i] * b;
    }
    __syncthreads();
  }
  #pragma unroll
  for (int i = 0; i < 8; i++) {
    int n = n0 + ty + 8 * i;
    if (n < N_NODES) Hout[(size_t)n * OUT_CH + tx] = acc[i];
  }
}

// ---------------- e_src2/e_dst2 per node (H=1) -----------------------------
__global__ __launch_bounds__(256) void edot2(const float* __restrict__ h2,
                                             const float* __restrict__ a_src,
                                             const float* __restrict__ a_dst,
                                             float* __restrict__ es,
                                             float* __restrict__ ed) {
  int n = blockIdx.x * 256 + threadIdx.x;
  if (n >= N_NODES) return;
  const float4* hp = reinterpret_cast<const float4*>(h2 + (size_t)n * OUT_CH);
  const float4* ap = reinterpret_cast<const float4*>(a_src);
  const float4* bp = reinterpret_cast<const float4*>(a_dst);
  float s = 0.f, d = 0.f;
  #pragma unroll
  for (int q = 0; q < 8; q++) {
    float4 hv = hp[q], av = ap[q], dv = bp[q];
    s += hv.x * av.x + hv.y * av.y + hv.z * av.z + hv.w * av.w;
    d += hv.x * dv.x + hv.y * dv.y + hv.z * dv.z + hv.w * dv.w;
  }
  es[n] = s; ed[n] = d;
}

// ------ layer-2 aggregation: one wave per node, unrolled, fused pool -------
__global__ __launch_bounds__(256) void agg2(const int* __restrict__ roff,
                                            const int* __restrict__ ssrc,
                                            const float* __restrict__ es,
                                            const float* __restrict__ ed,
                                            const float* __restrict__ h2,
                                            const float* __restrict__ b2,
                                            const int* __restrict__ batch,
                                            unsigned* __restrict__ pooled) {
  __shared__ float lds[4][64][2];    // [wave][edge][0]=ex, [1]=src bits
  const int n = (blockIdx.x * 256 + threadIdx.x) >> 6;
  if (n >= N_NODES) return;
  const int wslot = threadIdx.x >> 6;
  const int lane = threadIdx.x & 63;
  const int c = lane & 31;
  const int hb = lane >> 5;
  const int beg = roff[n];
  const int deg = roff[n + 1] - beg;
  const int g = batch[n];

  if (deg == 0) {
    if (lane < 32) {
      float v = b2[c];
      v = v > 0.f ? v : expm1f(v);
      atomicMax(&pooled[g * OUT_CH + c], fmap(v));
    }
    return;
  }

  float acc = 0.f, dtot;

  if (deg <= 64) {
    const int active = (lane < deg);
    const int src = ssrc[beg + (active ? lane : 0)];
    const float edv = ed[n];
    float a = active ? leaky(es[src] + edv) : -1e30f;
    float m = a;
    #pragma unroll
    for (int o = 1; o < 64; o <<= 1) m = fmaxf(m, __shfl_xor(m, o));
    float ex = expf(a - m);
    float d = ex;
    #pragma unroll
    for (int o = 1; o < 64; o <<= 1) d += __shfl_xor(d, o);
    dtot = d;
    lds[wslot][lane][0] = ex;
    lds[wslot][lane][1] = __int_as_float(src);
    // per half-wave: edges j = hb, hb+2, ... ; 4-edge unroll
    int j = hb;
    for (; j + 6 < deg; j += 8) {
      int s0 = __float_as_int(lds[wslot][j + 0][1]);
      int s1 = __float_as_int(lds[wslot][j + 2][1]);
      int s2 = __float_as_int(lds[wslot][j + 4][1]);
      int s3 = __float_as_int(lds[wslot][j + 6][1]);
      float c0 = lds[wslot][j + 0][0];
      float c1 = lds[wslot][j + 2][0];
      float c2 = lds[wslot][j + 4][0];
      float c3 = lds[wslot][j + 6][0];
      float v0 = h2[(size_t)s0 * OUT_CH + c];
      float v1 = h2[(size_t)s1 * OUT_CH + c];
      float v2 = h2[(size_t)s2 * OUT_CH + c];
      float v3 = h2[(size_t)s3 * OUT_CH + c];
      acc = fmaf(v0, c0, acc);
      acc = fmaf(v1, c1, acc);
      acc = fmaf(v2, c2, acc);
      acc = fmaf(v3, c3, acc);
    }
    for (; j < deg; j += 2) {
      int sj = __float_as_int(lds[wslot][j][1]);
      acc = fmaf(h2[(size_t)sj * OUT_CH + c], lds[wslot][j][0], acc);
    }
  } else {
    // slow fallback: redundant per-lane scalars
    const float edv = ed[n];
    float m = -1e30f;
    for (int j = beg; j < beg + deg; j++)
      m = fmaxf(m, leaky(es[ssrc[j]] + edv));
    float d = 0.f;
    for (int j = beg + hb; j < beg + deg; j += 2) {
      int src = ssrc[j];
      float ex = expf(leaky(es[src] + edv) - m);
      acc = fmaf(h2[(size_t)src * OUT_CH + c], ex, acc);
      d += ex;
    }
    d += __shfl_xor(d, 32);
    dtot = d;
  }

  acc += __shfl_xor(acc, 32);
  if (lane < 32) {
    float v = acc / (dtot + 1e-16f) + b2[c];
    v = v > 0.f ? v : expm1f(v);
    atomicMax(&pooled[g * OUT_CH + c], fmap(v));
  }
}

// -------- final: out[g,c] = relu(pooled[g,:] @ fc_w[:,c] + fc_b[c]) --------
__global__ __launch_bounds__(256) void final_k(const unsigned* __restrict__ pooled,
                                               const float* __restrict__ fc_w,
                                               const float* __restrict__ fc_b,
                                               float* __restrict__ out) {
  int idx = blockIdx.x * 256 + threadIdx.x;
  if (idx >= N_GRAPHS * OUT_CH) return;
  int g = idx >> 5, c = idx & 31;
  float s = fc_b[c];
  #pragma unroll
  for (int k = 0; k < OUT_CH; k++) {
    unsigned u = pooled[g * OUT_CH + k];
    float p = (u == 0u) ? 0.f : funmap(u);
    s += p * fc_w[k * OUT_CH + c];
  }
  out[idx] = s > 0.f ? s : 0.f;
}

extern "C" void kernel_launch(void* const* d_in, const int* in_sizes, int n_in,
                              void* d_out, int out_size, void* d_ws, size_t ws_size,
                              hipStream_t stream) {
  const float* x      = (const float*)d_in[0];
  const int*   ei     = (const int*)d_in[1];
  const int*   batch  = (const int*)d_in[2];
  const float* W1     = (const float*)d_in[4];
  const float* a_src1 = (const float*)d_in[5];
  const float* a_dst1 = (const float*)d_in[6];
  const float* b1     = (const float*)d_in[7];
  const float* W2     = (const float*)d_in[8];
  const float* a_src2 = (const float*)d_in[9];
  const float* a_dst2 = (const float*)d_in[10];
  const float* b2     = (const float*)d_in[11];
  const float* fc_w   = (const float*)d_in[12];
  const float* fc_b   = (const float*)d_in[13];
  float* out = (float*)d_out;

  // ---- workspace layout (<= 136 MB) ----
  char* ws = (char*)d_ws;
  float* h1   = (float*)(ws);                 // 64 MB; h2 reuses after agg1
  float* act1 = (float*)(ws + 64000000);      // 64 MB
  char*  S    = ws + 128000000;               // ~7.9 MB small region
  int*   ssrc   = (int*)(S);                  // 3.2 MB
  int*   roff   = (int*)(S + 3200000);        // 200,004 B
  int*   deg    = (int*)(S + 3400064);        // 200,000 B
  int*   cursor = (int*)(S + 3600064);        // 200,000 B
  float* es1    = (float*)(S + 3800064);      // 2 MB
  float* ed1    = (float*)(S + 5800064);      // 2 MB
  int*   bsum   = (int*)(S + 7800064);        // 784 B
  unsigned* pooled = (unsigned*)(S + 7801600);// 64 KB
  float* h2  = (float*)(ws);                  // 6.4 MB (h1 dead after agg1)
  float* es2 = es1; float* ed2 = ed1;         // es1/ed1 dead after agg1

  // ---- CSR build ----
  hipMemsetAsync(deg, 0, (size_t)N_NODES * 4, stream);
  hipMemsetAsync(cursor, 0, (size_t)N_NODES * 4, stream);
  hist_k   <<<(N_EDGES + 255) / 256, 256, 0, stream>>>(ei, deg);
  scan_blk <<<NBLK_SCAN, 256, 0, stream>>>(deg, roff, bsum);
  scan_top <<<1, 256, 0, stream>>>(bsum);
  scan_add <<<NBLK_SCAN, 256, 0, stream>>>(roff, bsum);
  scatter_k<<<(N_EDGES + 255) / 256, 256, 0, stream>>>(ei, roff, cursor, ssrc);

  // ---- layer 1 ----
  gemm1<<<dim3(HC / 64, (N_NODES + 63) / 64), dim3(16, 16), 0, stream>>>(x, W1, h1);
  edot1<<<(N_NODES * HEADS + 255) / 256, 256, 0, stream>>>(h1, a_src1, a_dst1, es1, ed1);
  agg1 <<<(N_NODES * 64 + 255) / 256, 256, 0, stream>>>(roff, ssrc, es1, ed1, h1, b1, act1);

  // ---- layer 2 ----
  hipMemsetAsync(pooled, 0, (size_t)N_GRAPHS * OUT_CH * 4, stream);
  gemm2<<<dim3((N_NODES + 63) / 64), dim3(32, 8), 0, stream>>>(act1, W2, h2);
  edot2<<<(N_NODES + 255) / 256, 256, 0, stream>>>(h2, a_src2, a_dst2, es2, ed2);
  agg2 <<<(N_NODES * 64 + 255) / 256, 256, 0, stream>>>(roff, ssrc, es2, ed2, h2, b2, batch, pooled);
  final_k<<<(N_GRAPHS * OUT_CH + 255) / 256, 256, 0, stream>>>(pooled, fc_w, fc_b, out);
}